// Round 10
// baseline (157.459 us; speedup 1.0000x reference)
//
#include <hip/hip_runtime.h>
#include <hip/hip_fp16.h>

// ---------- small vector helpers ----------
struct V3 { float x, y, z; };

__device__ __forceinline__ V3 v3add(V3 a, V3 b){ return {a.x+b.x, a.y+b.y, a.z+b.z}; }
__device__ __forceinline__ V3 v3sub(V3 a, V3 b){ return {a.x-b.x, a.y-b.y, a.z-b.z}; }
__device__ __forceinline__ V3 v3scale(V3 a, float s){ return {a.x*s, a.y*s, a.z*s}; }
__device__ __forceinline__ V3 v3mul(V3 a, V3 b){ return {a.x*b.x, a.y*b.y, a.z*b.z}; }
__device__ __forceinline__ float dot3(V3 a, V3 b){ return fmaf(a.x,b.x, fmaf(a.y,b.y, a.z*b.z)); }
__device__ __forceinline__ V3 nrm3(V3 a){
    float s = rsqrtf(fmaxf(dot3(a,a), 1e-20f));
    return v3scale(a, s);
}

// ---------- texel-count offsets ----------
#define OFF0 0
#define OFF1 1572864
#define OFF2 1966080
#define OFF3 2064384
#define OFF4 2088960
#define OFF5 2095104
#define DIFF_OFF 2096640
#define SPEC_DIFF_COUNT 2098176

// ---- pair layout (mid tier, 16B fp16 pair blocks) ----
struct __align__(16) PairBlock { __half2 h01, h23, h45, h67; };
#define FG_OFF 2098176
#define TOTAL_BLOCKS 2163712
#define PACK_ONLY_BLOCKS 2098176
#define WS_BYTES_FULL  ((size_t)TOTAL_BLOCKS * 16)
#define WS_BYTES_PACK  ((size_t)PACK_ONLY_BLOCKS * 16)

// ---- q10 layout (top tier): 16B quad per texel, 12 x 10-bit UNORM ----
#define Q10_FG_COUNT 65536
#define Q10_COUNT (SPEC_DIFF_COUNT + Q10_FG_COUNT)      // 2,163,712 quads
// appendix: compact 1-uint-per-texel q10 for diffuse(1536) + mip5(1536) + mip4(6144)
#define APP_DIFF 0
#define APP_M5   1536
#define APP_M4   3072
#define APP_UINTS 9216                                   // 36,864 B
#define WS_BYTES_Q10L ((size_t)Q10_COUNT * 16 + (size_t)APP_UINTS * 4)  // 34,656,256

// ---------- cube face / uv ----------
__device__ __forceinline__ void cube_face_uv(V3 d, int& face, float& u, float& v){
    float ax = fabsf(d.x), ay = fabsf(d.y), az = fabsf(d.z);
    bool is_x = (ax >= ay) && (ax >= az);
    bool is_y = (!is_x) && (ay >= az);
    face = is_x ? (d.x >= 0.f ? 0 : 1)
                : (is_y ? (d.y >= 0.f ? 2 : 3)
                        : (d.z >= 0.f ? 4 : 5));
    float ma = fmaxf(is_x ? ax : (is_y ? ay : az), 1e-20f);
    float un = (face == 0) ? -d.z : (face == 1) ? d.z : (face == 5) ? -d.x : d.x;
    float vn = (face == 2) ?  d.z : (face == 3) ? -d.z : -d.y;
    float inv = 1.0f / ma;
    u = un * inv;
    v = vn * inv;
}

// ---------- bilinear coords ----------
__device__ __forceinline__ void quad_coord_cube(float u, float v, int R,
                                                int& xq, int& yq, float& fx, float& fy){
    float Rf = (float)R;
    float tu = fmaf(fmaf(u, 0.5f, 0.5f), Rf, -0.5f);
    float tv = fmaf(fmaf(v, 0.5f, 0.5f), Rf, -0.5f);
    float x0f = floorf(tu), y0f = floorf(tv);
    fx = tu - x0f; fy = tv - y0f;
    int x0 = (int)x0f, y0 = (int)y0f;
    fx = (x0 < 0) ? 0.f : fx;
    fy = (y0 < 0) ? 0.f : fy;
    xq = min(max(x0, 0), R-1);
    yq = min(max(y0, 0), R-1);
}

__device__ __forceinline__ void quad_coord_2d(float u, float v, int W, int H,
                                              int& xq, int& yq, float& fx, float& fy){
    float tu = fmaf(u, (float)W, -0.5f);
    float tv = fmaf(v, (float)H, -0.5f);
    float x0f = floorf(tu), y0f = floorf(tv);
    fx = tu - x0f; fy = tv - y0f;
    int x0 = (int)x0f, y0 = (int)y0f;
    fx = (x0 < 0) ? 0.f : fx;
    fy = (y0 < 0) ? 0.f : fy;
    xq = min(max(x0, 0), W-1);
    yq = min(max(y0, 0), H-1);
}

// ---------- q10 blend (4 packed texels: 00,01,10,11) ----------
__device__ __forceinline__ V3 q10_blend(uint4 q, float fx, float fy){
    float w00 = (1.f-fx)*(1.f-fy), w01 = fx*(1.f-fy);
    float w10 = (1.f-fx)*fy,       w11 = fx*fy;
    float r = (float)(q.x & 1023u)*w00 + (float)(q.y & 1023u)*w01
            + (float)(q.z & 1023u)*w10 + (float)(q.w & 1023u)*w11;
    float g = (float)((q.x>>10) & 1023u)*w00 + (float)((q.y>>10) & 1023u)*w01
            + (float)((q.z>>10) & 1023u)*w10 + (float)((q.w>>10) & 1023u)*w11;
    float b = (float)((q.x>>20) & 1023u)*w00 + (float)((q.y>>20) & 1023u)*w01
            + (float)((q.z>>20) & 1023u)*w10 + (float)((q.w>>20) & 1023u)*w11;
    const float s = 1.0f/1023.0f;
    return { r*s, g*s, b*s };
}

__device__ __forceinline__ void q10_fg(uint4 q, float fx, float fy,
                                       float& fa, float& fb){
    float w00 = (1.f-fx)*(1.f-fy), w01 = fx*(1.f-fy);
    float w10 = (1.f-fx)*fy,       w11 = fx*fy;
    float a00 = (float)(q.x & 1023u),        b00 = (float)((q.x>>10) & 1023u);
    float a01 = (float)((q.x>>20) & 1023u),  b01 = (float)(q.y & 1023u);
    float a10 = (float)((q.y>>10) & 1023u),  b10 = (float)((q.y>>20) & 1023u);
    float a11 = (float)(q.z & 1023u),        b11 = (float)((q.z>>10) & 1023u);
    const float s = 1.0f/1023.0f;
    fa = (a00*w00 + a01*w01 + a10*w10 + a11*w11) * s;
    fb = (b00*w00 + b01*w01 + b10*w10 + b11*w11) * s;
}

// ---------- LDS compact-q10 bilinear (4-corner clamp, matches reference) ----------
__device__ __forceinline__ V3 lds_bilin(const unsigned* lds, int base, int R,
                                        int face, float u, float v){
    float Rf = (float)R;
    float tu = fmaf(fmaf(u, 0.5f, 0.5f), Rf, -0.5f);
    float tv = fmaf(fmaf(v, 0.5f, 0.5f), Rf, -0.5f);
    float x0f = floorf(tu), y0f = floorf(tv);
    float fx = tu - x0f, fy = tv - y0f;
    int x0 = min(max((int)x0f,     0), R-1);
    int x1 = min(max((int)x0f + 1, 0), R-1);
    int y0 = min(max((int)y0f,     0), R-1);
    int y1 = min(max((int)y0f + 1, 0), R-1);
    const unsigned* fb = lds + base + face * R * R;
    uint4 q = make_uint4(fb[y0*R + x0], fb[y0*R + x1],
                         fb[y1*R + x0], fb[y1*R + x1]);
    // when (int)x0f<0 both x-corners clamp to 0 so fx value is irrelevant; same for y
    return q10_blend(q, fx, fy);
}

// ---------- pair-layout sampling (mid tier) ----------
__device__ __forceinline__ void pair_extract(const PairBlock& pb, V3& lo, V3& hi){
    lo.x = __low2float(pb.h01);  lo.y = __high2float(pb.h01); lo.z = __low2float(pb.h23);
    hi.x = __high2float(pb.h23); hi.y = __low2float(pb.h45);  hi.z = __high2float(pb.h45);
}

__device__ __forceinline__ V3 bilinear_pairtex(const PairBlock* __restrict__ lvl, int R,
                                               int face, float u, float v){
    float Rf = (float)R;
    float tu = fmaf(fmaf(u, 0.5f, 0.5f), Rf, -0.5f);
    float tv = fmaf(fmaf(v, 0.5f, 0.5f), Rf, -0.5f);
    float x0f = floorf(tu), y0f = floorf(tv);
    float fx = tu - x0f,    fy = tv - y0f;
    int x0 = (int)x0f;
    fx = (x0 < 0) ? 0.f : fx;
    int xb  = min(max(x0, 0), R-1);
    int y0i = min(max((int)y0f,     0), R-1);
    int y1i = min(max((int)y0f + 1, 0), R-1);
    const PairBlock* fb = lvl + (size_t)face * R * R;
    PairBlock b0 = fb[(size_t)y0i * R + xb];
    PairBlock b1 = fb[(size_t)y1i * R + xb];
    V3 l0, h0, l1, h1;
    pair_extract(b0, l0, h0);
    pair_extract(b1, l1, h1);
    V3 r0 = { l0.x + (h0.x-l0.x)*fx, l0.y + (h0.y-l0.y)*fx, l0.z + (h0.z-l0.z)*fx };
    V3 r1 = { l1.x + (h1.x-l1.x)*fx, l1.y + (h1.y-l1.y)*fx, l1.z + (h1.z-l1.z)*fx };
    return { r0.x + (r1.x-r0.x)*fy, r0.y + (r1.y-r0.y)*fy, r0.z + (r1.z-r0.z)*fy };
}

__device__ __forceinline__ void sample_fg_pair(const float4* __restrict__ fgp,
                                               float u, float v, float& fa, float& fb){
    const int W = 256, H = 256;
    float tu = fmaf(u, (float)W, -0.5f);
    float tv = fmaf(v, (float)H, -0.5f);
    float x0f = floorf(tu), y0f = floorf(tv);
    float fx = tu - x0f,    fy = tv - y0f;
    int x0 = (int)x0f;
    fx = (x0 < 0) ? 0.f : fx;
    int xb  = min(max(x0, 0), W-1);
    int y0i = min(max((int)y0f,     0), H-1);
    int y1i = min(max((int)y0f + 1, 0), H-1);
    float4 r0 = fgp[(size_t)y0i * W + xb];
    float4 r1 = fgp[(size_t)y1i * W + xb];
    float t0a = r0.x + (r0.z - r0.x)*fx, t0b = r0.y + (r0.w - r0.y)*fx;
    float t1a = r1.x + (r1.z - r1.x)*fx, t1b = r1.y + (r1.w - r1.y)*fx;
    fa = t0a + (t1a - t0a)*fy;
    fb = t0b + (t1b - t0b)*fy;
}

// ---------- raw-tier sampling ----------
__device__ __forceinline__ V3 bilinear_cube3(const float* __restrict__ tex, int R,
                                             int face, float u, float v){
    float Rf = (float)R;
    float tu = fmaf(fmaf(u, 0.5f, 0.5f), Rf, -0.5f);
    float tv = fmaf(fmaf(v, 0.5f, 0.5f), Rf, -0.5f);
    float x0 = floorf(tu), y0 = floorf(tv);
    float fx = tu - x0,    fy = tv - y0;
    int x0i = min(max((int)x0,     0), R-1);
    int x1i = min(max((int)x0 + 1, 0), R-1);
    int y0i = min(max((int)y0,     0), R-1);
    int y1i = min(max((int)y0 + 1, 0), R-1);
    const float* base = tex + (size_t)face * R * R * 3;
    const float* r0 = base + (size_t)y0i * R * 3;
    const float* r1 = base + (size_t)y1i * R * 3;
    float a0 = r0[3*x0i], a1 = r0[3*x0i+1], a2 = r0[3*x0i+2];
    float b0 = r0[3*x1i], b1 = r0[3*x1i+1], b2 = r0[3*x1i+2];
    float d0 = r1[3*x0i], d1 = r1[3*x0i+1], d2 = r1[3*x0i+2];
    float e0 = r1[3*x1i], e1 = r1[3*x1i+1], e2 = r1[3*x1i+2];
    float w00 = (1.f-fx)*(1.f-fy), w01 = fx*(1.f-fy);
    float w10 = (1.f-fx)*fy,       w11 = fx*fy;
    V3 out;
    out.x = a0*w00 + b0*w01 + d0*w10 + e0*w11;
    out.y = a1*w00 + b1*w01 + d1*w10 + e1*w11;
    out.z = a2*w00 + b2*w01 + d2*w10 + e2*w11;
    return out;
}

__device__ __forceinline__ void sample_fg(const float* __restrict__ lut,
                                          float u, float v, float& fa, float& fb){
    const int W = 256, H = 256;
    float tu = fmaf(u, (float)W, -0.5f);
    float tv = fmaf(v, (float)H, -0.5f);
    float x0 = floorf(tu), y0 = floorf(tv);
    float fx = tu - x0,    fy = tv - y0;
    int x0i = min(max((int)x0,     0), W-1);
    int x1i = min(max((int)x0 + 1, 0), W-1);
    int y0i = min(max((int)y0,     0), H-1);
    int y1i = min(max((int)y0 + 1, 0), H-1);
    const float2* l2 = (const float2*)lut;
    float2 a = l2[(size_t)y0i*W + x0i];
    float2 b = l2[(size_t)y0i*W + x1i];
    float2 d = l2[(size_t)y1i*W + x0i];
    float2 e = l2[(size_t)y1i*W + x1i];
    float w00 = (1.f-fx)*(1.f-fy), w01 = fx*(1.f-fy);
    float w10 = (1.f-fx)*fy,       w11 = fx*fy;
    fa = a.x*w00 + b.x*w01 + d.x*w10 + e.x*w11;
    fb = a.y*w00 + b.y*w01 + d.y*w10 + e.y*w11;
}

// ---------- linear -> srgb ----------
__device__ __forceinline__ float lin2srgb(float x){
    float xs = (x > 0.0031308f) ? x : 1.0f;
    float p  = __builtin_amdgcn_exp2f(__builtin_amdgcn_logf(xs) * (1.0f/2.4f));
    return (x > 0.0031308f) ? fmaf(1.055f, p, -0.055f) : 12.92f * x;
}

__device__ __forceinline__ float clamp01(float x){ return fminf(fmaxf(x, 0.f), 1.f); }

// ---------- per-pixel precomputed state ----------
struct PixPre {
    V3 diff_alb, spec_alb;
    int sface; float su, sv;
    int dface; float du, dv;
    int offA, RA, offB, RB; float f;
    float ndotv, rough;
};

__device__ __forceinline__ PixPre pre_pixel(
    int i,
    const float* __restrict__ gb_pos, const float* __restrict__ gb_normal,
    const float* __restrict__ basecolor, const float* __restrict__ metallic,
    const float* __restrict__ roughness, V3 vp)
{
    V3 pos = { gb_pos[3*i],    gb_pos[3*i+1],    gb_pos[3*i+2] };
    V3 nrm = { gb_normal[3*i], gb_normal[3*i+1], gb_normal[3*i+2] };
    V3 bc  = { basecolor[3*i], basecolor[3*i+1], basecolor[3*i+2] };
    float m = metallic[i];
    float r = roughness[i];

    V3 wo = nrm3(v3sub(vp, pos));
    float ndv_raw = dot3(wo, nrm);
    V3 refl = nrm3(v3sub(v3scale(nrm, 2.0f*ndv_raw), wo));

    PixPre p;
    float one_m = 1.0f - m;
    p.diff_alb = v3scale(bc, one_m);
    p.spec_alb = { fmaf(m, bc.x, 0.04f*one_m),
                   fmaf(m, bc.y, 0.04f*one_m),
                   fmaf(m, bc.z, 0.04f*one_m) };
    p.ndotv = fmaxf(ndv_raw, 0.0001f);
    p.rough = r;

    const float MIN_R = 0.08f, MAX_R = 0.5f;
    float lo = (fminf(fmaxf(r, MIN_R), MAX_R) - MIN_R) / (MAX_R - MIN_R) * 4.0f;
    float hi = (fminf(fmaxf(r, MAX_R), 1.0f) - MAX_R) / (1.0f - MAX_R) + 4.0f;
    float mip = (r < MAX_R) ? lo : hi;
    mip = fminf(fmaxf(mip, 0.0f), 5.0f);
    int l0 = min((int)mip, 5);
    p.f = mip - (float)l0;
    int l1 = min(l0 + 1, 5);

    int offA = OFF0;
    offA = (l0 == 1) ? OFF1 : offA; offA = (l0 == 2) ? OFF2 : offA;
    offA = (l0 == 3) ? OFF3 : offA; offA = (l0 == 4) ? OFF4 : offA;
    offA = (l0 == 5) ? OFF5 : offA;
    int offB = OFF0;
    offB = (l1 == 1) ? OFF1 : offB; offB = (l1 == 2) ? OFF2 : offB;
    offB = (l1 == 3) ? OFF3 : offB; offB = (l1 == 4) ? OFF4 : offB;
    offB = (l1 == 5) ? OFF5 : offB;
    p.offA = offA; p.RA = 512 >> l0;
    p.offB = offB; p.RB = 512 >> l1;

    cube_face_uv(nrm, p.dface, p.du, p.dv);
    cube_face_uv(refl, p.sface, p.su, p.sv);
    return p;
}

// ---------- q10 pack helper ----------
__device__ __forceinline__ unsigned pk3(float a, float b, float c){
    unsigned ia = __float2uint_rn(fminf(fmaxf(a, 0.f), 1.f) * 1023.f);
    unsigned ib = __float2uint_rn(fminf(fmaxf(b, 0.f), 1.f) * 1023.f);
    unsigned ic = __float2uint_rn(fminf(fmaxf(c, 0.f), 1.f) * 1023.f);
    return ia | (ib << 10) | (ic << 20);
}

// ---------- q10+appendix pre-pass ----------
__global__ __launch_bounds__(256)
void pack_q10l_kernel(const float* __restrict__ s0, const float* __restrict__ s1,
                      const float* __restrict__ s2, const float* __restrict__ s3,
                      const float* __restrict__ s4, const float* __restrict__ s5,
                      const float* __restrict__ diffuse, const float* __restrict__ fg_lut,
                      uint4* __restrict__ qws)
{
    int t = blockIdx.x * blockDim.x + threadIdx.x;
    if (t >= Q10_COUNT + APP_UINTS) return;
    if (t >= Q10_COUNT) {
        // appendix: compact per-texel q10 for diffuse / mip5 / mip4
        int local = t - Q10_COUNT;
        const float* src; int idx;
        if      (local < APP_M5) { src = diffuse; idx = local; }
        else if (local < APP_M4) { src = s5;      idx = local - APP_M5; }
        else                     { src = s4;      idx = local - APP_M4; }
        ((unsigned*)(qws + Q10_COUNT))[local] = pk3(src[3*idx], src[3*idx+1], src[3*idx+2]);
        return;
    }
    if (t >= SPEC_DIFF_COUNT) {
        int local = t - SPEC_DIFF_COUNT;
        int x = local & 255, y = local >> 8;
        int i00 = local;
        int i01 = (x == 255) ? local : local + 1;
        int i10 = (y == 255) ? local : local + 256;
        int i11 = (x == 255) ? i10 : i10 + 1;
        uint4 q;
        q.x = pk3(fg_lut[2*i00], fg_lut[2*i00+1], fg_lut[2*i01]);
        q.y = pk3(fg_lut[2*i01+1], fg_lut[2*i10], fg_lut[2*i10+1]);
        q.z = pk3(fg_lut[2*i11], fg_lut[2*i11+1], 0.f);
        q.w = 0u;
        qws[t] = q;
        return;
    }
    const float* src; int local; int Rm, Rsh;
    if      (t >= DIFF_OFF) { src = diffuse; local = t - DIFF_OFF; Rm = 15;  Rsh = 4; }
    else if (t >= OFF5)     { src = s5;      local = t - OFF5;     Rm = 15;  Rsh = 4; }
    else if (t >= OFF4)     { src = s4;      local = t - OFF4;     Rm = 31;  Rsh = 5; }
    else if (t >= OFF3)     { src = s3;      local = t - OFF3;     Rm = 63;  Rsh = 6; }
    else if (t >= OFF2)     { src = s2;      local = t - OFF2;     Rm = 127; Rsh = 7; }
    else if (t >= OFF1)     { src = s1;      local = t - OFF1;     Rm = 255; Rsh = 8; }
    else                    { src = s0;      local = t;            Rm = 511; Rsh = 9; }
    int x = local & Rm;
    int y = (local >> Rsh) & Rm;
    int i00 = local;
    int i01 = (x == Rm) ? local : local + 1;
    int i10 = (y == Rm) ? local : local + (Rm + 1);
    int i11 = (x == Rm) ? i10 : i10 + 1;
    uint4 q;
    q.x = pk3(src[3*i00], src[3*i00+1], src[3*i00+2]);
    q.y = pk3(src[3*i01], src[3*i01+1], src[3*i01+2]);
    q.z = pk3(src[3*i10], src[3*i10+1], src[3*i10+2]);
    q.w = pk3(src[3*i11], src[3*i11+1], src[3*i11+2]);
    qws[t] = q;
}

// ---------- spec sampler: LDS for mips 4/5, global quads otherwise ----------
__device__ __forceinline__ V3 sample_spec(const uint4* __restrict__ qws,
                                          const unsigned* lds,
                                          int off, int R, int face, float u, float v){
    if (R <= 32) {
        int base = (R == 16) ? APP_M5 : APP_M4;
        return lds_bilin(lds, base, R, face, u, v);
    }
    int x, y; float fx, fy;
    quad_coord_cube(u, v, R, x, y, fx, fy);
    size_t q = (size_t)off + (size_t)face * R * R + (size_t)y * R + x;
    return q10_blend(qws[q], fx, fy);
}

// ---------- q10+LDS main kernel: 1 px/thread ----------
__global__ __launch_bounds__(256)
void envlight_q10l(const float* __restrict__ gb_pos,
                   const float* __restrict__ gb_normal,
                   const float* __restrict__ basecolor,
                   const float* __restrict__ metallic,
                   const float* __restrict__ roughness,
                   const float* __restrict__ view_pos,
                   const uint4* __restrict__ qws,
                   float* __restrict__ out,
                   int n)
{
    __shared__ unsigned lds_small[APP_UINTS];   // 36 KB
    {
        const uint4* app4 = qws + Q10_COUNT;
        uint4* l4 = (uint4*)lds_small;
        for (int k = threadIdx.x; k < APP_UINTS/4; k += 256)
            l4[k] = app4[k];
    }
    __syncthreads();

    int i = blockIdx.x * blockDim.x + threadIdx.x;
    if (i >= n) return;
    V3 vp = { view_pos[0], view_pos[1], view_pos[2] };
    PixPre p = pre_pixel(i, gb_pos, gb_normal, basecolor, metallic, roughness, vp);

    // fg (always global, L2-resident) — issue first
    int fx_, fy_; float ffx, ffy;
    quad_coord_2d(p.ndotv, p.rough, 256, 256, fx_, fy_, ffx, ffy);
    uint4 F = qws[(size_t)SPEC_DIFF_COUNT + (size_t)fy_ * 256 + fx_];

    V3 specA = sample_spec(qws, lds_small, p.offA, p.RA, p.sface, p.su, p.sv);
    V3 specB = sample_spec(qws, lds_small, p.offB, p.RB, p.sface, p.su, p.sv);
    V3 ambient = lds_bilin(lds_small, APP_DIFF, 16, p.dface, p.du, p.dv);

    float fa, fb;
    q10_fg(F, ffx, ffy, fa, fb);

    V3 spec = { specA.x + (specB.x - specA.x) * p.f,
                specA.y + (specB.y - specA.y) * p.f,
                specA.z + (specB.z - specA.z) * p.f };
    V3 reflc = { fmaf(p.spec_alb.x, fa, fb),
                 fmaf(p.spec_alb.y, fa, fb),
                 fmaf(p.spec_alb.z, fa, fb) };
    V3 rgb = v3add(v3mul(spec, reflc), v3mul(ambient, p.diff_alb));

    out[3*i+0] = lin2srgb(clamp01(rgb.x));
    out[3*i+1] = lin2srgb(clamp01(rgb.y));
    out[3*i+2] = lin2srgb(clamp01(rgb.z));
}

// ---------- pair pre-pass (mid tier) ----------
__global__ __launch_bounds__(256)
void pack_kernel(const float* __restrict__ s0, const float* __restrict__ s1,
                 const float* __restrict__ s2, const float* __restrict__ s3,
                 const float* __restrict__ s4, const float* __restrict__ s5,
                 const float* __restrict__ diffuse, const float* __restrict__ fg_lut,
                 PairBlock* __restrict__ ws, int total)
{
    int t = blockIdx.x * blockDim.x + threadIdx.x;
    if (t >= total) return;
    if (t >= FG_OFF) {
        int local = t - FG_OFF;
        int x = local & 255;
        int nb = (x == 255) ? local : local + 1;
        float4 v = make_float4(fg_lut[2*local], fg_lut[2*local+1],
                               fg_lut[2*nb],    fg_lut[2*nb+1]);
        ((float4*)ws)[t] = v;
        return;
    }
    const float* src; int local; int Rmask;
    if      (t >= DIFF_OFF) { src = diffuse; local = t - DIFF_OFF; Rmask = 15;  }
    else if (t >= OFF5)     { src = s5;      local = t - OFF5;     Rmask = 15;  }
    else if (t >= OFF4)     { src = s4;      local = t - OFF4;     Rmask = 31;  }
    else if (t >= OFF3)     { src = s3;      local = t - OFF3;     Rmask = 63;  }
    else if (t >= OFF2)     { src = s2;      local = t - OFF2;     Rmask = 127; }
    else if (t >= OFF1)     { src = s1;      local = t - OFF1;     Rmask = 255; }
    else                    { src = s0;      local = t;            Rmask = 511; }
    int nb = ((local & Rmask) == Rmask) ? local : local + 1;
    float ar = src[3*local], ag = src[3*local+1], ab = src[3*local+2];
    float br = src[3*nb],    bg = src[3*nb+1],    bb = src[3*nb+2];
    PairBlock pb;
    pb.h01 = __floats2half2_rn(ar, ag);
    pb.h23 = __floats2half2_rn(ab, br);
    pb.h45 = __floats2half2_rn(bg, bb);
    pb.h67 = __floats2half2_rn(0.f, 0.f);
    ws[t] = pb;
}

// ---------- pair main kernel (mid tier) ----------
template <bool FGPAIR>
__global__ __launch_bounds__(256)
void envlight_pair(const float* __restrict__ gb_pos,
                   const float* __restrict__ gb_normal,
                   const float* __restrict__ basecolor,
                   const float* __restrict__ metallic,
                   const float* __restrict__ roughness,
                   const float* __restrict__ view_pos,
                   const float* __restrict__ fg_lut,
                   const PairBlock* __restrict__ ws,
                   float* __restrict__ out,
                   int n)
{
    int i = blockIdx.x * blockDim.x + threadIdx.x;
    if (i >= n) return;
    V3 vp = { view_pos[0], view_pos[1], view_pos[2] };
    PixPre p = pre_pixel(i, gb_pos, gb_normal, basecolor, metallic, roughness, vp);
    V3 specA   = bilinear_pairtex(ws + p.offA, p.RA, p.sface, p.su, p.sv);
    V3 specB   = bilinear_pairtex(ws + p.offB, p.RB, p.sface, p.su, p.sv);
    V3 ambient = bilinear_pairtex(ws + DIFF_OFF, 16, p.dface, p.du, p.dv);
    float fa, fb;
    if (FGPAIR) sample_fg_pair((const float4*)(ws + FG_OFF), p.ndotv, p.rough, fa, fb);
    else        sample_fg(fg_lut, p.ndotv, p.rough, fa, fb);
    V3 spec = { specA.x + (specB.x - specA.x) * p.f,
                specA.y + (specB.y - specA.y) * p.f,
                specA.z + (specB.z - specA.z) * p.f };
    V3 reflc = { fmaf(p.spec_alb.x, fa, fb),
                 fmaf(p.spec_alb.y, fa, fb),
                 fmaf(p.spec_alb.z, fa, fb) };
    V3 rgb = v3add(v3mul(spec, reflc), v3mul(ambient, p.diff_alb));
    out[3*i+0] = lin2srgb(clamp01(rgb.x));
    out[3*i+1] = lin2srgb(clamp01(rgb.y));
    out[3*i+2] = lin2srgb(clamp01(rgb.z));
}

// ---------- raw fallback ----------
__global__ __launch_bounds__(256)
void envlight_fallback(const float* __restrict__ gb_pos,
                       const float* __restrict__ gb_normal,
                       const float* __restrict__ basecolor,
                       const float* __restrict__ metallic,
                       const float* __restrict__ roughness,
                       const float* __restrict__ view_pos,
                       const float* __restrict__ diffuse,
                       const float* __restrict__ fg_lut,
                       const float* __restrict__ s0, const float* __restrict__ s1,
                       const float* __restrict__ s2, const float* __restrict__ s3,
                       const float* __restrict__ s4, const float* __restrict__ s5,
                       float* __restrict__ out, int n)
{
    int i = blockIdx.x * blockDim.x + threadIdx.x;
    if (i >= n) return;
    V3 vp = { view_pos[0], view_pos[1], view_pos[2] };
    PixPre p = pre_pixel(i, gb_pos, gb_normal, basecolor, metallic, roughness, vp);
    int l0 = 0;
    l0 = (p.offA == OFF1) ? 1 : l0; l0 = (p.offA == OFF2) ? 2 : l0;
    l0 = (p.offA == OFF3) ? 3 : l0; l0 = (p.offA == OFF4) ? 4 : l0;
    l0 = (p.offA == OFF5) ? 5 : l0;
    int l1 = 0;
    l1 = (p.offB == OFF1) ? 1 : l1; l1 = (p.offB == OFF2) ? 2 : l1;
    l1 = (p.offB == OFF3) ? 3 : l1; l1 = (p.offB == OFF4) ? 4 : l1;
    l1 = (p.offB == OFF5) ? 5 : l1;
    const float* tA = s0;
    tA = (l0 == 1) ? s1 : tA; tA = (l0 == 2) ? s2 : tA;
    tA = (l0 == 3) ? s3 : tA; tA = (l0 == 4) ? s4 : tA; tA = (l0 == 5) ? s5 : tA;
    const float* tB = s0;
    tB = (l1 == 1) ? s1 : tB; tB = (l1 == 2) ? s2 : tB;
    tB = (l1 == 3) ? s3 : tB; tB = (l1 == 4) ? s4 : tB; tB = (l1 == 5) ? s5 : tB;
    V3 ambient = bilinear_cube3(diffuse, 16, p.dface, p.du, p.dv);
    V3 specA   = bilinear_cube3(tA, p.RA, p.sface, p.su, p.sv);
    V3 specB   = bilinear_cube3(tB, p.RB, p.sface, p.su, p.sv);
    float fa, fb;
    sample_fg(fg_lut, p.ndotv, p.rough, fa, fb);
    V3 spec = { specA.x + (specB.x - specA.x) * p.f,
                specA.y + (specB.y - specA.y) * p.f,
                specA.z + (specB.z - specA.z) * p.f };
    V3 reflc = { fmaf(p.spec_alb.x, fa, fb),
                 fmaf(p.spec_alb.y, fa, fb),
                 fmaf(p.spec_alb.z, fa, fb) };
    V3 rgb = v3add(v3mul(spec, reflc), v3mul(ambient, p.diff_alb));
    out[3*i+0] = lin2srgb(clamp01(rgb.x));
    out[3*i+1] = lin2srgb(clamp01(rgb.y));
    out[3*i+2] = lin2srgb(clamp01(rgb.z));
}

extern "C" void kernel_launch(void* const* d_in, const int* in_sizes, int n_in,
                              void* d_out, int out_size, void* d_ws, size_t ws_size,
                              hipStream_t stream) {
    const float* gb_pos    = (const float*)d_in[0];
    const float* gb_normal = (const float*)d_in[1];
    const float* basecolor = (const float*)d_in[2];
    const float* metallic  = (const float*)d_in[3];
    const float* roughness = (const float*)d_in[4];
    const float* view_pos  = (const float*)d_in[5];
    const float* diffuse   = (const float*)d_in[6];
    const float* fg_lut    = (const float*)d_in[7];
    const float* s0        = (const float*)d_in[8];
    const float* s1        = (const float*)d_in[9];
    const float* s2        = (const float*)d_in[10];
    const float* s3        = (const float*)d_in[11];
    const float* s4        = (const float*)d_in[12];
    const float* s5        = (const float*)d_in[13];
    float* out = (float*)d_out;

    int n = in_sizes[0] / 3;
    int block = 256;
    int grid = (n + block - 1) / block;

    if (ws_size >= WS_BYTES_Q10L) {
        uint4* qws = (uint4*)d_ws;
        int ptotal = Q10_COUNT + APP_UINTS;
        int pgrid = (ptotal + block - 1) / block;
        pack_q10l_kernel<<<pgrid, block, 0, stream>>>(s0, s1, s2, s3, s4, s5,
                                                      diffuse, fg_lut, qws);
        envlight_q10l<<<grid, block, 0, stream>>>(gb_pos, gb_normal, basecolor,
            metallic, roughness, view_pos, qws, out, n);
    } else if (ws_size >= WS_BYTES_PACK) {
        bool full = ws_size >= WS_BYTES_FULL;
        PairBlock* ws = (PairBlock*)d_ws;
        int total = full ? TOTAL_BLOCKS : PACK_ONLY_BLOCKS;
        int pgrid = (total + block - 1) / block;
        pack_kernel<<<pgrid, block, 0, stream>>>(s0, s1, s2, s3, s4, s5,
                                                 diffuse, fg_lut, ws, total);
        if (full)
            envlight_pair<true><<<grid, block, 0, stream>>>(gb_pos, gb_normal,
                basecolor, metallic, roughness, view_pos, fg_lut, ws, out, n);
        else
            envlight_pair<false><<<grid, block, 0, stream>>>(gb_pos, gb_normal,
                basecolor, metallic, roughness, view_pos, fg_lut, ws, out, n);
    } else {
        envlight_fallback<<<grid, block, 0, stream>>>(gb_pos, gb_normal, basecolor,
            metallic, roughness, view_pos, diffuse, fg_lut,
            s0, s1, s2, s3, s4, s5, out, n);
    }
}

// Round 11
// 155.111 us; speedup vs baseline: 1.0151x; 1.0151x over previous
//
#include <hip/hip_runtime.h>
#include <hip/hip_fp16.h>

// ---------- small vector helpers ----------
struct V3 { float x, y, z; };

__device__ __forceinline__ V3 v3add(V3 a, V3 b){ return {a.x+b.x, a.y+b.y, a.z+b.z}; }
__device__ __forceinline__ V3 v3sub(V3 a, V3 b){ return {a.x-b.x, a.y-b.y, a.z-b.z}; }
__device__ __forceinline__ V3 v3scale(V3 a, float s){ return {a.x*s, a.y*s, a.z*s}; }
__device__ __forceinline__ V3 v3mul(V3 a, V3 b){ return {a.x*b.x, a.y*b.y, a.z*b.z}; }
__device__ __forceinline__ float dot3(V3 a, V3 b){ return fmaf(a.x,b.x, fmaf(a.y,b.y, a.z*b.z)); }
__device__ __forceinline__ V3 nrm3(V3 a){
    float s = rsqrtf(fmaxf(dot3(a,a), 1e-20f));
    return v3scale(a, s);
}

// ---------- texel-count offsets ----------
#define OFF0 0
#define OFF1 1572864
#define OFF2 1966080
#define OFF3 2064384
#define OFF4 2088960
#define OFF5 2095104
#define DIFF_OFF 2096640
#define SPEC_DIFF_COUNT 2098176

// ---- pair layout (mid tier, 16B fp16 pair blocks) ----
struct __align__(16) PairBlock { __half2 h01, h23, h45, h67; };
#define FG_OFF 2098176
#define TOTAL_BLOCKS 2163712
#define PACK_ONLY_BLOCKS 2098176
#define WS_BYTES_FULL  ((size_t)TOTAL_BLOCKS * 16)
#define WS_BYTES_PACK  ((size_t)PACK_ONLY_BLOCKS * 16)

// ---- q10 layout (top tier): 16B quad per texel, 12 x 10-bit UNORM ----
#define Q10_FG_COUNT 65536
#define Q10_COUNT (SPEC_DIFF_COUNT + Q10_FG_COUNT)      // 2,163,712 quads
// appendix: compact 1-uint-per-texel q10 for diffuse(1536) + mip5(1536) = 12,288 B
#define APP_DIFF 0
#define APP_M5   1536
#define APP_UINTS 3072
#define WS_BYTES_Q10M ((size_t)Q10_COUNT * 16 + (size_t)APP_UINTS * 4)  // 34,631,680

// ---------- cube face / uv ----------
__device__ __forceinline__ void cube_face_uv(V3 d, int& face, float& u, float& v){
    float ax = fabsf(d.x), ay = fabsf(d.y), az = fabsf(d.z);
    bool is_x = (ax >= ay) && (ax >= az);
    bool is_y = (!is_x) && (ay >= az);
    face = is_x ? (d.x >= 0.f ? 0 : 1)
                : (is_y ? (d.y >= 0.f ? 2 : 3)
                        : (d.z >= 0.f ? 4 : 5));
    float ma = fmaxf(is_x ? ax : (is_y ? ay : az), 1e-20f);
    float un = (face == 0) ? -d.z : (face == 1) ? d.z : (face == 5) ? -d.x : d.x;
    float vn = (face == 2) ?  d.z : (face == 3) ? -d.z : -d.y;
    float inv = 1.0f / ma;
    u = un * inv;
    v = vn * inv;
}

// ---------- bilinear coords ----------
__device__ __forceinline__ void quad_coord_cube(float u, float v, int R,
                                                int& xq, int& yq, float& fx, float& fy){
    float Rf = (float)R;
    float tu = fmaf(fmaf(u, 0.5f, 0.5f), Rf, -0.5f);
    float tv = fmaf(fmaf(v, 0.5f, 0.5f), Rf, -0.5f);
    float x0f = floorf(tu), y0f = floorf(tv);
    fx = tu - x0f; fy = tv - y0f;
    int x0 = (int)x0f, y0 = (int)y0f;
    fx = (x0 < 0) ? 0.f : fx;
    fy = (y0 < 0) ? 0.f : fy;
    xq = min(max(x0, 0), R-1);
    yq = min(max(y0, 0), R-1);
}

__device__ __forceinline__ void quad_coord_2d(float u, float v, int W, int H,
                                              int& xq, int& yq, float& fx, float& fy){
    float tu = fmaf(u, (float)W, -0.5f);
    float tv = fmaf(v, (float)H, -0.5f);
    float x0f = floorf(tu), y0f = floorf(tv);
    fx = tu - x0f; fy = tv - y0f;
    int x0 = (int)x0f, y0 = (int)y0f;
    fx = (x0 < 0) ? 0.f : fx;
    fy = (y0 < 0) ? 0.f : fy;
    xq = min(max(x0, 0), W-1);
    yq = min(max(y0, 0), H-1);
}

// ---------- q10 blend (4 packed texels: 00,01,10,11) ----------
__device__ __forceinline__ V3 q10_blend(uint4 q, float fx, float fy){
    float w00 = (1.f-fx)*(1.f-fy), w01 = fx*(1.f-fy);
    float w10 = (1.f-fx)*fy,       w11 = fx*fy;
    float r = (float)(q.x & 1023u)*w00 + (float)(q.y & 1023u)*w01
            + (float)(q.z & 1023u)*w10 + (float)(q.w & 1023u)*w11;
    float g = (float)((q.x>>10) & 1023u)*w00 + (float)((q.y>>10) & 1023u)*w01
            + (float)((q.z>>10) & 1023u)*w10 + (float)((q.w>>10) & 1023u)*w11;
    float b = (float)((q.x>>20) & 1023u)*w00 + (float)((q.y>>20) & 1023u)*w01
            + (float)((q.z>>20) & 1023u)*w10 + (float)((q.w>>20) & 1023u)*w11;
    const float s = 1.0f/1023.0f;
    return { r*s, g*s, b*s };
}

__device__ __forceinline__ void q10_fg(uint4 q, float fx, float fy,
                                       float& fa, float& fb){
    float w00 = (1.f-fx)*(1.f-fy), w01 = fx*(1.f-fy);
    float w10 = (1.f-fx)*fy,       w11 = fx*fy;
    float a00 = (float)(q.x & 1023u),        b00 = (float)((q.x>>10) & 1023u);
    float a01 = (float)((q.x>>20) & 1023u),  b01 = (float)(q.y & 1023u);
    float a10 = (float)((q.y>>10) & 1023u),  b10 = (float)((q.y>>20) & 1023u);
    float a11 = (float)(q.z & 1023u),        b11 = (float)((q.z>>10) & 1023u);
    const float s = 1.0f/1023.0f;
    fa = (a00*w00 + a01*w01 + a10*w10 + a11*w11) * s;
    fb = (b00*w00 + b01*w01 + b10*w10 + b11*w11) * s;
}

// ---------- LDS compact-q10 bilinear (4-corner clamp) ----------
__device__ __forceinline__ V3 lds_bilin(const unsigned* lds, int base, int R,
                                        int face, float u, float v){
    float Rf = (float)R;
    float tu = fmaf(fmaf(u, 0.5f, 0.5f), Rf, -0.5f);
    float tv = fmaf(fmaf(v, 0.5f, 0.5f), Rf, -0.5f);
    float x0f = floorf(tu), y0f = floorf(tv);
    float fx = tu - x0f, fy = tv - y0f;
    int x0 = min(max((int)x0f,     0), R-1);
    int x1 = min(max((int)x0f + 1, 0), R-1);
    int y0 = min(max((int)y0f,     0), R-1);
    int y1 = min(max((int)y0f + 1, 0), R-1);
    const unsigned* fb = lds + base + face * R * R;
    uint4 q = make_uint4(fb[y0*R + x0], fb[y0*R + x1],
                         fb[y1*R + x0], fb[y1*R + x1]);
    // when (int)x0f<0 both x-corners clamp to 0 so fx value is irrelevant; same for y
    return q10_blend(q, fx, fy);
}

// ---------- pair-layout sampling (mid tier) ----------
__device__ __forceinline__ void pair_extract(const PairBlock& pb, V3& lo, V3& hi){
    lo.x = __low2float(pb.h01);  lo.y = __high2float(pb.h01); lo.z = __low2float(pb.h23);
    hi.x = __high2float(pb.h23); hi.y = __low2float(pb.h45);  hi.z = __high2float(pb.h45);
}

__device__ __forceinline__ V3 bilinear_pairtex(const PairBlock* __restrict__ lvl, int R,
                                               int face, float u, float v){
    float Rf = (float)R;
    float tu = fmaf(fmaf(u, 0.5f, 0.5f), Rf, -0.5f);
    float tv = fmaf(fmaf(v, 0.5f, 0.5f), Rf, -0.5f);
    float x0f = floorf(tu), y0f = floorf(tv);
    float fx = tu - x0f,    fy = tv - y0f;
    int x0 = (int)x0f;
    fx = (x0 < 0) ? 0.f : fx;
    int xb  = min(max(x0, 0), R-1);
    int y0i = min(max((int)y0f,     0), R-1);
    int y1i = min(max((int)y0f + 1, 0), R-1);
    const PairBlock* fb = lvl + (size_t)face * R * R;
    PairBlock b0 = fb[(size_t)y0i * R + xb];
    PairBlock b1 = fb[(size_t)y1i * R + xb];
    V3 l0, h0, l1, h1;
    pair_extract(b0, l0, h0);
    pair_extract(b1, l1, h1);
    V3 r0 = { l0.x + (h0.x-l0.x)*fx, l0.y + (h0.y-l0.y)*fx, l0.z + (h0.z-l0.z)*fx };
    V3 r1 = { l1.x + (h1.x-l1.x)*fx, l1.y + (h1.y-l1.y)*fx, l1.z + (h1.z-l1.z)*fx };
    return { r0.x + (r1.x-r0.x)*fy, r0.y + (r1.y-r0.y)*fy, r0.z + (r1.z-r0.z)*fy };
}

__device__ __forceinline__ void sample_fg_pair(const float4* __restrict__ fgp,
                                               float u, float v, float& fa, float& fb){
    const int W = 256, H = 256;
    float tu = fmaf(u, (float)W, -0.5f);
    float tv = fmaf(v, (float)H, -0.5f);
    float x0f = floorf(tu), y0f = floorf(tv);
    float fx = tu - x0f,    fy = tv - y0f;
    int x0 = (int)x0f;
    fx = (x0 < 0) ? 0.f : fx;
    int xb  = min(max(x0, 0), W-1);
    int y0i = min(max((int)y0f,     0), H-1);
    int y1i = min(max((int)y0f + 1, 0), H-1);
    float4 r0 = fgp[(size_t)y0i * W + xb];
    float4 r1 = fgp[(size_t)y1i * W + xb];
    float t0a = r0.x + (r0.z - r0.x)*fx, t0b = r0.y + (r0.w - r0.y)*fx;
    float t1a = r1.x + (r1.z - r1.x)*fx, t1b = r1.y + (r1.w - r1.y)*fx;
    fa = t0a + (t1a - t0a)*fy;
    fb = t0b + (t1b - t0b)*fy;
}

// ---------- raw-tier sampling ----------
__device__ __forceinline__ V3 bilinear_cube3(const float* __restrict__ tex, int R,
                                             int face, float u, float v){
    float Rf = (float)R;
    float tu = fmaf(fmaf(u, 0.5f, 0.5f), Rf, -0.5f);
    float tv = fmaf(fmaf(v, 0.5f, 0.5f), Rf, -0.5f);
    float x0 = floorf(tu), y0 = floorf(tv);
    float fx = tu - x0,    fy = tv - y0;
    int x0i = min(max((int)x0,     0), R-1);
    int x1i = min(max((int)x0 + 1, 0), R-1);
    int y0i = min(max((int)y0,     0), R-1);
    int y1i = min(max((int)y0 + 1, 0), R-1);
    const float* base = tex + (size_t)face * R * R * 3;
    const float* r0 = base + (size_t)y0i * R * 3;
    const float* r1 = base + (size_t)y1i * R * 3;
    float a0 = r0[3*x0i], a1 = r0[3*x0i+1], a2 = r0[3*x0i+2];
    float b0 = r0[3*x1i], b1 = r0[3*x1i+1], b2 = r0[3*x1i+2];
    float d0 = r1[3*x0i], d1 = r1[3*x0i+1], d2 = r1[3*x0i+2];
    float e0 = r1[3*x1i], e1 = r1[3*x1i+1], e2 = r1[3*x1i+2];
    float w00 = (1.f-fx)*(1.f-fy), w01 = fx*(1.f-fy);
    float w10 = (1.f-fx)*fy,       w11 = fx*fy;
    V3 out;
    out.x = a0*w00 + b0*w01 + d0*w10 + e0*w11;
    out.y = a1*w00 + b1*w01 + d1*w10 + e1*w11;
    out.z = a2*w00 + b2*w01 + d2*w10 + e2*w11;
    return out;
}

__device__ __forceinline__ void sample_fg(const float* __restrict__ lut,
                                          float u, float v, float& fa, float& fb){
    const int W = 256, H = 256;
    float tu = fmaf(u, (float)W, -0.5f);
    float tv = fmaf(v, (float)H, -0.5f);
    float x0 = floorf(tu), y0 = floorf(tv);
    float fx = tu - x0,    fy = tv - y0;
    int x0i = min(max((int)x0,     0), W-1);
    int x1i = min(max((int)x0 + 1, 0), W-1);
    int y0i = min(max((int)y0,     0), H-1);
    int y1i = min(max((int)y0 + 1, 0), H-1);
    const float2* l2 = (const float2*)lut;
    float2 a = l2[(size_t)y0i*W + x0i];
    float2 b = l2[(size_t)y0i*W + x1i];
    float2 d = l2[(size_t)y1i*W + x0i];
    float2 e = l2[(size_t)y1i*W + x1i];
    float w00 = (1.f-fx)*(1.f-fy), w01 = fx*(1.f-fy);
    float w10 = (1.f-fx)*fy,       w11 = fx*fy;
    fa = a.x*w00 + b.x*w01 + d.x*w10 + e.x*w11;
    fb = a.y*w00 + b.y*w01 + d.y*w10 + e.y*w11;
}

// ---------- linear -> srgb ----------
__device__ __forceinline__ float lin2srgb(float x){
    float xs = (x > 0.0031308f) ? x : 1.0f;
    float p  = __builtin_amdgcn_exp2f(__builtin_amdgcn_logf(xs) * (1.0f/2.4f));
    return (x > 0.0031308f) ? fmaf(1.055f, p, -0.055f) : 12.92f * x;
}

__device__ __forceinline__ float clamp01(float x){ return fminf(fmaxf(x, 0.f), 1.f); }

// ---------- per-pixel precomputed state ----------
struct PixPre {
    V3 diff_alb, spec_alb;
    int sface; float su, sv;
    int dface; float du, dv;
    int offA, RA, offB, RB; float f;
    float ndotv, rough;
};

__device__ __forceinline__ PixPre pre_pixel(
    int i,
    const float* __restrict__ gb_pos, const float* __restrict__ gb_normal,
    const float* __restrict__ basecolor, const float* __restrict__ metallic,
    const float* __restrict__ roughness, V3 vp)
{
    V3 pos = { gb_pos[3*i],    gb_pos[3*i+1],    gb_pos[3*i+2] };
    V3 nrm = { gb_normal[3*i], gb_normal[3*i+1], gb_normal[3*i+2] };
    V3 bc  = { basecolor[3*i], basecolor[3*i+1], basecolor[3*i+2] };
    float m = metallic[i];
    float r = roughness[i];

    V3 wo = nrm3(v3sub(vp, pos));
    float ndv_raw = dot3(wo, nrm);
    V3 refl = nrm3(v3sub(v3scale(nrm, 2.0f*ndv_raw), wo));

    PixPre p;
    float one_m = 1.0f - m;
    p.diff_alb = v3scale(bc, one_m);
    p.spec_alb = { fmaf(m, bc.x, 0.04f*one_m),
                   fmaf(m, bc.y, 0.04f*one_m),
                   fmaf(m, bc.z, 0.04f*one_m) };
    p.ndotv = fmaxf(ndv_raw, 0.0001f);
    p.rough = r;

    const float MIN_R = 0.08f, MAX_R = 0.5f;
    float lo = (fminf(fmaxf(r, MIN_R), MAX_R) - MIN_R) / (MAX_R - MIN_R) * 4.0f;
    float hi = (fminf(fmaxf(r, MAX_R), 1.0f) - MAX_R) / (1.0f - MAX_R) + 4.0f;
    float mip = (r < MAX_R) ? lo : hi;
    mip = fminf(fmaxf(mip, 0.0f), 5.0f);
    int l0 = min((int)mip, 5);
    p.f = mip - (float)l0;
    int l1 = min(l0 + 1, 5);

    int offA = OFF0;
    offA = (l0 == 1) ? OFF1 : offA; offA = (l0 == 2) ? OFF2 : offA;
    offA = (l0 == 3) ? OFF3 : offA; offA = (l0 == 4) ? OFF4 : offA;
    offA = (l0 == 5) ? OFF5 : offA;
    int offB = OFF0;
    offB = (l1 == 1) ? OFF1 : offB; offB = (l1 == 2) ? OFF2 : offB;
    offB = (l1 == 3) ? OFF3 : offB; offB = (l1 == 4) ? OFF4 : offB;
    offB = (l1 == 5) ? OFF5 : offB;
    p.offA = offA; p.RA = 512 >> l0;
    p.offB = offB; p.RB = 512 >> l1;

    cube_face_uv(nrm, p.dface, p.du, p.dv);
    cube_face_uv(refl, p.sface, p.su, p.sv);
    return p;
}

// ---------- q10 pack helper ----------
__device__ __forceinline__ unsigned pk3(float a, float b, float c){
    unsigned ia = __float2uint_rn(fminf(fmaxf(a, 0.f), 1.f) * 1023.f);
    unsigned ib = __float2uint_rn(fminf(fmaxf(b, 0.f), 1.f) * 1023.f);
    unsigned ic = __float2uint_rn(fminf(fmaxf(c, 0.f), 1.f) * 1023.f);
    return ia | (ib << 10) | (ic << 20);
}

// ---------- q10+appendix pre-pass ----------
__global__ __launch_bounds__(256)
void pack_q10m_kernel(const float* __restrict__ s0, const float* __restrict__ s1,
                      const float* __restrict__ s2, const float* __restrict__ s3,
                      const float* __restrict__ s4, const float* __restrict__ s5,
                      const float* __restrict__ diffuse, const float* __restrict__ fg_lut,
                      uint4* __restrict__ qws)
{
    int t = blockIdx.x * blockDim.x + threadIdx.x;
    if (t >= Q10_COUNT + APP_UINTS) return;
    if (t >= Q10_COUNT) {
        // appendix: compact per-texel q10 for diffuse / mip5
        int local = t - Q10_COUNT;
        const float* src; int idx;
        if (local < APP_M5) { src = diffuse; idx = local; }
        else                { src = s5;      idx = local - APP_M5; }
        ((unsigned*)(qws + Q10_COUNT))[local] = pk3(src[3*idx], src[3*idx+1], src[3*idx+2]);
        return;
    }
    if (t >= SPEC_DIFF_COUNT) {
        int local = t - SPEC_DIFF_COUNT;
        int x = local & 255, y = local >> 8;
        int i00 = local;
        int i01 = (x == 255) ? local : local + 1;
        int i10 = (y == 255) ? local : local + 256;
        int i11 = (x == 255) ? i10 : i10 + 1;
        uint4 q;
        q.x = pk3(fg_lut[2*i00], fg_lut[2*i00+1], fg_lut[2*i01]);
        q.y = pk3(fg_lut[2*i01+1], fg_lut[2*i10], fg_lut[2*i10+1]);
        q.z = pk3(fg_lut[2*i11], fg_lut[2*i11+1], 0.f);
        q.w = 0u;
        qws[t] = q;
        return;
    }
    const float* src; int local; int Rm, Rsh;
    if      (t >= DIFF_OFF) { src = diffuse; local = t - DIFF_OFF; Rm = 15;  Rsh = 4; }
    else if (t >= OFF5)     { src = s5;      local = t - OFF5;     Rm = 15;  Rsh = 4; }
    else if (t >= OFF4)     { src = s4;      local = t - OFF4;     Rm = 31;  Rsh = 5; }
    else if (t >= OFF3)     { src = s3;      local = t - OFF3;     Rm = 63;  Rsh = 6; }
    else if (t >= OFF2)     { src = s2;      local = t - OFF2;     Rm = 127; Rsh = 7; }
    else if (t >= OFF1)     { src = s1;      local = t - OFF1;     Rm = 255; Rsh = 8; }
    else                    { src = s0;      local = t;            Rm = 511; Rsh = 9; }
    int x = local & Rm;
    int y = (local >> Rsh) & Rm;
    int i00 = local;
    int i01 = (x == Rm) ? local : local + 1;
    int i10 = (y == Rm) ? local : local + (Rm + 1);
    int i11 = (x == Rm) ? i10 : i10 + 1;
    uint4 q;
    q.x = pk3(src[3*i00], src[3*i00+1], src[3*i00+2]);
    q.y = pk3(src[3*i01], src[3*i01+1], src[3*i01+2]);
    q.z = pk3(src[3*i10], src[3*i10+1], src[3*i10+2]);
    q.w = pk3(src[3*i11], src[3*i11+1], src[3*i11+2]);
    qws[t] = q;
}

// ---------- spec sampler: LDS for mip5 (R==16), global quads otherwise ----------
__device__ __forceinline__ V3 sample_spec(const uint4* __restrict__ qws,
                                          const unsigned* lds,
                                          int off, int R, int face, float u, float v){
    if (R == 16)
        return lds_bilin(lds, APP_M5, 16, face, u, v);
    int x, y; float fx, fy;
    quad_coord_cube(u, v, R, x, y, fx, fy);
    size_t q = (size_t)off + (size_t)face * R * R + (size_t)y * R + x;
    return q10_blend(qws[q], fx, fy);
}

// ---------- q10+small-LDS main kernel: 1 px/thread ----------
__global__ __launch_bounds__(256)
void envlight_q10m(const float* __restrict__ gb_pos,
                   const float* __restrict__ gb_normal,
                   const float* __restrict__ basecolor,
                   const float* __restrict__ metallic,
                   const float* __restrict__ roughness,
                   const float* __restrict__ view_pos,
                   const uint4* __restrict__ qws,
                   float* __restrict__ out,
                   int n)
{
    __shared__ unsigned lds_small[APP_UINTS];   // 12 KB: diffuse + mip5
    {
        const uint4* app4 = qws + Q10_COUNT;
        uint4* l4 = (uint4*)lds_small;
        for (int k = threadIdx.x; k < APP_UINTS/4; k += 256)
            l4[k] = app4[k];
    }
    __syncthreads();

    int i = blockIdx.x * blockDim.x + threadIdx.x;
    if (i >= n) return;
    V3 vp = { view_pos[0], view_pos[1], view_pos[2] };
    PixPre p = pre_pixel(i, gb_pos, gb_normal, basecolor, metallic, roughness, vp);

    // fg (global, L2-resident) — issue first
    int fx_, fy_; float ffx, ffy;
    quad_coord_2d(p.ndotv, p.rough, 256, 256, fx_, fy_, ffx, ffy);
    uint4 F = qws[(size_t)SPEC_DIFF_COUNT + (size_t)fy_ * 256 + fx_];

    V3 specA = sample_spec(qws, lds_small, p.offA, p.RA, p.sface, p.su, p.sv);
    V3 specB = sample_spec(qws, lds_small, p.offB, p.RB, p.sface, p.su, p.sv);
    V3 ambient = lds_bilin(lds_small, APP_DIFF, 16, p.dface, p.du, p.dv);

    float fa, fb;
    q10_fg(F, ffx, ffy, fa, fb);

    V3 spec = { specA.x + (specB.x - specA.x) * p.f,
                specA.y + (specB.y - specA.y) * p.f,
                specA.z + (specB.z - specA.z) * p.f };
    V3 reflc = { fmaf(p.spec_alb.x, fa, fb),
                 fmaf(p.spec_alb.y, fa, fb),
                 fmaf(p.spec_alb.z, fa, fb) };
    V3 rgb = v3add(v3mul(spec, reflc), v3mul(ambient, p.diff_alb));

    out[3*i+0] = lin2srgb(clamp01(rgb.x));
    out[3*i+1] = lin2srgb(clamp01(rgb.y));
    out[3*i+2] = lin2srgb(clamp01(rgb.z));
}

// ---------- pair pre-pass (mid tier) ----------
__global__ __launch_bounds__(256)
void pack_kernel(const float* __restrict__ s0, const float* __restrict__ s1,
                 const float* __restrict__ s2, const float* __restrict__ s3,
                 const float* __restrict__ s4, const float* __restrict__ s5,
                 const float* __restrict__ diffuse, const float* __restrict__ fg_lut,
                 PairBlock* __restrict__ ws, int total)
{
    int t = blockIdx.x * blockDim.x + threadIdx.x;
    if (t >= total) return;
    if (t >= FG_OFF) {
        int local = t - FG_OFF;
        int x = local & 255;
        int nb = (x == 255) ? local : local + 1;
        float4 v = make_float4(fg_lut[2*local], fg_lut[2*local+1],
                               fg_lut[2*nb],    fg_lut[2*nb+1]);
        ((float4*)ws)[t] = v;
        return;
    }
    const float* src; int local; int Rmask;
    if      (t >= DIFF_OFF) { src = diffuse; local = t - DIFF_OFF; Rmask = 15;  }
    else if (t >= OFF5)     { src = s5;      local = t - OFF5;     Rmask = 15;  }
    else if (t >= OFF4)     { src = s4;      local = t - OFF4;     Rmask = 31;  }
    else if (t >= OFF3)     { src = s3;      local = t - OFF3;     Rmask = 63;  }
    else if (t >= OFF2)     { src = s2;      local = t - OFF2;     Rmask = 127; }
    else if (t >= OFF1)     { src = s1;      local = t - OFF1;     Rmask = 255; }
    else                    { src = s0;      local = t;            Rmask = 511; }
    int nb = ((local & Rmask) == Rmask) ? local : local + 1;
    float ar = src[3*local], ag = src[3*local+1], ab = src[3*local+2];
    float br = src[3*nb],    bg = src[3*nb+1],    bb = src[3*nb+2];
    PairBlock pb;
    pb.h01 = __floats2half2_rn(ar, ag);
    pb.h23 = __floats2half2_rn(ab, br);
    pb.h45 = __floats2half2_rn(bg, bb);
    pb.h67 = __floats2half2_rn(0.f, 0.f);
    ws[t] = pb;
}

// ---------- pair main kernel (mid tier) ----------
template <bool FGPAIR>
__global__ __launch_bounds__(256)
void envlight_pair(const float* __restrict__ gb_pos,
                   const float* __restrict__ gb_normal,
                   const float* __restrict__ basecolor,
                   const float* __restrict__ metallic,
                   const float* __restrict__ roughness,
                   const float* __restrict__ view_pos,
                   const float* __restrict__ fg_lut,
                   const PairBlock* __restrict__ ws,
                   float* __restrict__ out,
                   int n)
{
    int i = blockIdx.x * blockDim.x + threadIdx.x;
    if (i >= n) return;
    V3 vp = { view_pos[0], view_pos[1], view_pos[2] };
    PixPre p = pre_pixel(i, gb_pos, gb_normal, basecolor, metallic, roughness, vp);
    V3 specA   = bilinear_pairtex(ws + p.offA, p.RA, p.sface, p.su, p.sv);
    V3 specB   = bilinear_pairtex(ws + p.offB, p.RB, p.sface, p.su, p.sv);
    V3 ambient = bilinear_pairtex(ws + DIFF_OFF, 16, p.dface, p.du, p.dv);
    float fa, fb;
    if (FGPAIR) sample_fg_pair((const float4*)(ws + FG_OFF), p.ndotv, p.rough, fa, fb);
    else        sample_fg(fg_lut, p.ndotv, p.rough, fa, fb);
    V3 spec = { specA.x + (specB.x - specA.x) * p.f,
                specA.y + (specB.y - specA.y) * p.f,
                specA.z + (specB.z - specA.z) * p.f };
    V3 reflc = { fmaf(p.spec_alb.x, fa, fb),
                 fmaf(p.spec_alb.y, fa, fb),
                 fmaf(p.spec_alb.z, fa, fb) };
    V3 rgb = v3add(v3mul(spec, reflc), v3mul(ambient, p.diff_alb));
    out[3*i+0] = lin2srgb(clamp01(rgb.x));
    out[3*i+1] = lin2srgb(clamp01(rgb.y));
    out[3*i+2] = lin2srgb(clamp01(rgb.z));
}

// ---------- raw fallback ----------
__global__ __launch_bounds__(256)
void envlight_fallback(const float* __restrict__ gb_pos,
                       const float* __restrict__ gb_normal,
                       const float* __restrict__ basecolor,
                       const float* __restrict__ metallic,
                       const float* __restrict__ roughness,
                       const float* __restrict__ view_pos,
                       const float* __restrict__ diffuse,
                       const float* __restrict__ fg_lut,
                       const float* __restrict__ s0, const float* __restrict__ s1,
                       const float* __restrict__ s2, const float* __restrict__ s3,
                       const float* __restrict__ s4, const float* __restrict__ s5,
                       float* __restrict__ out, int n)
{
    int i = blockIdx.x * blockDim.x + threadIdx.x;
    if (i >= n) return;
    V3 vp = { view_pos[0], view_pos[1], view_pos[2] };
    PixPre p = pre_pixel(i, gb_pos, gb_normal, basecolor, metallic, roughness, vp);
    int l0 = 0;
    l0 = (p.offA == OFF1) ? 1 : l0; l0 = (p.offA == OFF2) ? 2 : l0;
    l0 = (p.offA == OFF3) ? 3 : l0; l0 = (p.offA == OFF4) ? 4 : l0;
    l0 = (p.offA == OFF5) ? 5 : l0;
    int l1 = 0;
    l1 = (p.offB == OFF1) ? 1 : l1; l1 = (p.offB == OFF2) ? 2 : l1;
    l1 = (p.offB == OFF3) ? 3 : l1; l1 = (p.offB == OFF4) ? 4 : l1;
    l1 = (p.offB == OFF5) ? 5 : l1;
    const float* tA = s0;
    tA = (l0 == 1) ? s1 : tA; tA = (l0 == 2) ? s2 : tA;
    tA = (l0 == 3) ? s3 : tA; tA = (l0 == 4) ? s4 : tA; tA = (l0 == 5) ? s5 : tA;
    const float* tB = s0;
    tB = (l1 == 1) ? s1 : tB; tB = (l1 == 2) ? s2 : tB;
    tB = (l1 == 3) ? s3 : tB; tB = (l1 == 4) ? s4 : tB; tB = (l1 == 5) ? s5 : tB;
    V3 ambient = bilinear_cube3(diffuse, 16, p.dface, p.du, p.dv);
    V3 specA   = bilinear_cube3(tA, p.RA, p.sface, p.su, p.sv);
    V3 specB   = bilinear_cube3(tB, p.RB, p.sface, p.su, p.sv);
    float fa, fb;
    sample_fg(fg_lut, p.ndotv, p.rough, fa, fb);
    V3 spec = { specA.x + (specB.x - specA.x) * p.f,
                specA.y + (specB.y - specA.y) * p.f,
                specA.z + (specB.z - specA.z) * p.f };
    V3 reflc = { fmaf(p.spec_alb.x, fa, fb),
                 fmaf(p.spec_alb.y, fa, fb),
                 fmaf(p.spec_alb.z, fa, fb) };
    V3 rgb = v3add(v3mul(spec, reflc), v3mul(ambient, p.diff_alb));
    out[3*i+0] = lin2srgb(clamp01(rgb.x));
    out[3*i+1] = lin2srgb(clamp01(rgb.y));
    out[3*i+2] = lin2srgb(clamp01(rgb.z));
}

extern "C" void kernel_launch(void* const* d_in, const int* in_sizes, int n_in,
                              void* d_out, int out_size, void* d_ws, size_t ws_size,
                              hipStream_t stream) {
    const float* gb_pos    = (const float*)d_in[0];
    const float* gb_normal = (const float*)d_in[1];
    const float* basecolor = (const float*)d_in[2];
    const float* metallic  = (const float*)d_in[3];
    const float* roughness = (const float*)d_in[4];
    const float* view_pos  = (const float*)d_in[5];
    const float* diffuse   = (const float*)d_in[6];
    const float* fg_lut    = (const float*)d_in[7];
    const float* s0        = (const float*)d_in[8];
    const float* s1        = (const float*)d_in[9];
    const float* s2        = (const float*)d_in[10];
    const float* s3        = (const float*)d_in[11];
    const float* s4        = (const float*)d_in[12];
    const float* s5        = (const float*)d_in[13];
    float* out = (float*)d_out;

    int n = in_sizes[0] / 3;
    int block = 256;
    int grid = (n + block - 1) / block;

    if (ws_size >= WS_BYTES_Q10M) {
        uint4* qws = (uint4*)d_ws;
        int ptotal = Q10_COUNT + APP_UINTS;
        int pgrid = (ptotal + block - 1) / block;
        pack_q10m_kernel<<<pgrid, block, 0, stream>>>(s0, s1, s2, s3, s4, s5,
                                                      diffuse, fg_lut, qws);
        envlight_q10m<<<grid, block, 0, stream>>>(gb_pos, gb_normal, basecolor,
            metallic, roughness, view_pos, qws, out, n);
    } else if (ws_size >= WS_BYTES_PACK) {
        bool full = ws_size >= WS_BYTES_FULL;
        PairBlock* ws = (PairBlock*)d_ws;
        int total = full ? TOTAL_BLOCKS : PACK_ONLY_BLOCKS;
        int pgrid = (total + block - 1) / block;
        pack_kernel<<<pgrid, block, 0, stream>>>(s0, s1, s2, s3, s4, s5,
                                                 diffuse, fg_lut, ws, total);
        if (full)
            envlight_pair<true><<<grid, block, 0, stream>>>(gb_pos, gb_normal,
                basecolor, metallic, roughness, view_pos, fg_lut, ws, out, n);
        else
            envlight_pair<false><<<grid, block, 0, stream>>>(gb_pos, gb_normal,
                basecolor, metallic, roughness, view_pos, fg_lut, ws, out, n);
    } else {
        envlight_fallback<<<grid, block, 0, stream>>>(gb_pos, gb_normal, basecolor,
            metallic, roughness, view_pos, diffuse, fg_lut,
            s0, s1, s2, s3, s4, s5, out, n);
    }
}